// Round 8
// baseline (449.997 us; speedup 1.0000x reference)
//
#include <hip/hip_runtime.h>
#include <cstdint>
#include <cstddef>

// GAT layer, N=8192, F_in=512, F_out=64, fp32, int32 adjacency.
//   k_pack   : adj (268 MB int32) -> bitmask (8 MB), ballot-based, BW-bound.
//   k_wh     : Wh = h@W ; wh1/wh2 projections ; global max(wh2) via atomicMax ;
//              WhT_hi/WhT_lo = transposed 2-way bf16 split of Wh ([64 f][8192 j])
//   k_attend : per 16-row wave, stream 64-j tiles: p = bit ? exp(lrelu(.)-Mi) : 0
//              p in registers in MFMA A-frag layout; PV via 3x
//              mfma_f32_16x16x32_bf16 per (kstep,fblock): Ph*Whi + Pl*Whi + Ph*Wlo
//   k_merge  : out = sum(o)/sum(l) over JSPLIT partials
//
// R7 lesson: raw adj int4 loads (16B @ 32KB row stride) = 64-segment scatter
// per wave-load; vmcnt drain at each tile barrier stalled k_attend at ~137us.
// Bit-packing moves the one mandatory 268MB read into a coalesced BW-bound
// pass; k_attend's adj traffic drops 32x (1 uint64/lane/tile, L2-resident).

#define GAT_N    8192
#define GAT_FIN  512
#define GAT_F    64
#define TJ       64
#define JSPLIT   8
#define JCHUNK   (GAT_N / JSPLIT)     // 1024
#define NTILES   (JCHUNK / TJ)        // 16
#define NWORDS   (GAT_N / 64)         // 128 words per row

typedef __attribute__((ext_vector_type(8))) short short8;
typedef __attribute__((ext_vector_type(4))) float f32x4;

__device__ __forceinline__ float lrelu(float x) { return fmaxf(x, 0.2f * x); }

__device__ __forceinline__ unsigned enc_f32(float f) {
    unsigned b = __float_as_uint(f);
    return b ^ ((b & 0x80000000u) ? 0xFFFFFFFFu : 0x80000000u);
}
__device__ __forceinline__ float dec_f32(unsigned u) {
    return __uint_as_float(u ^ ((u & 0x80000000u) ? 0x80000000u : 0xFFFFFFFFu));
}
// truncation bf16 split (p >= 0 here, residual exact-capturable)
__device__ __forceinline__ short f2bf_trunc(float f) {
    return (short)(__float_as_uint(f) >> 16);
}
__device__ __forceinline__ float bfhi(float f) {
    return __uint_as_float(__float_as_uint(f) & 0xFFFF0000u);
}

__device__ __forceinline__ void gload_lds16(const void* g, void* l) {
    __builtin_amdgcn_global_load_lds(
        (const __attribute__((address_space(1))) void*)g,
        (__attribute__((address_space(3))) void*)l, 16, 0, 0);
}

// ---------------------------------------------------------------- kernel 0
// grid 1024, block 256 (4 waves). Wave w handles 256 consecutive uint64
// words; per iter 8 words: lane reads adj[word*64+lane] (256B/instr
// coalesced, 2KB in flight), ballot -> word, lane 0 stores 4x16B.
__global__ __launch_bounds__(256) void k_pack(
    const int* __restrict__ adj, unsigned long long* __restrict__ packed)
{
    const int lane = threadIdx.x & 63;
    const int wv   = blockIdx.x * 4 + (threadIdx.x >> 6);  // 4096 waves
    const size_t wbase = (size_t)wv * 256;
    for (int it = 0; it < 32; ++it) {
        const size_t w0 = wbase + (size_t)it * 8;
        const int* src = adj + w0 * 64 + lane;
        unsigned long long b0, b1, b2, b3, b4, b5, b6, b7;
        b0 = __ballot(src[0 * 64] > 0);
        b1 = __ballot(src[1 * 64] > 0);
        b2 = __ballot(src[2 * 64] > 0);
        b3 = __ballot(src[3 * 64] > 0);
        b4 = __ballot(src[4 * 64] > 0);
        b5 = __ballot(src[5 * 64] > 0);
        b6 = __ballot(src[6 * 64] > 0);
        b7 = __ballot(src[7 * 64] > 0);
        if (lane == 0) {
            ulonglong2* dst = (ulonglong2*)&packed[w0];
            dst[0] = {b0, b1};
            dst[1] = {b2, b3};
            dst[2] = {b4, b5};
            dst[3] = {b6, b7};
        }
    }
}

// ---------------------------------------------------------------- kernel 1
// grid 512, block 256: 16 rows/block, thread = (rp 0..15, f4 0..15).
// W staged in LDS 64-k chunks (2x16 KB dbuf); emits wh1/wh2/max and the
// transposed bf16 split WhT_hi/lo via a small LDS transpose.
__global__ __launch_bounds__(256) void k_wh(
    const float* __restrict__ h, const float* __restrict__ W,
    const float* __restrict__ a,
    float* __restrict__ wh1, float* __restrict__ wh2,
    unsigned int* __restrict__ mw2,
    unsigned short* __restrict__ whtHi, unsigned short* __restrict__ whtLo)
{
    __shared__ float sW[2][64 * GAT_F];       // 2 x 16 KB
    __shared__ unsigned short sTh[GAT_F][16]; // 2 KB
    __shared__ unsigned short sTl[GAT_F][16]; // 2 KB
    __shared__ unsigned int smax[16];
    const int tid = threadIdx.x;
    const size_t r0 = (size_t)blockIdx.x * 16;
    const int rp = tid >> 4;
    const int f4 = (tid & 15) * 4;

    const char* wsrc = (const char*)W;
    {   // stage chunk 0 (linear; reads below are broadcast, conflict-free)
        char* dst = (char*)sW[0];
#pragma unroll
        for (int c = 0; c < 4; ++c)
            gload_lds16(wsrc + (size_t)(tid + c * 256) * 16,
                        dst + (size_t)(tid + c * 256) * 16);
    }

    const float* ha = h + (r0 + rp) * GAT_FIN;
    float4 acc = {0.f, 0.f, 0.f, 0.f};

    for (int ck = 0; ck < 8; ++ck) {
        __syncthreads();
        if (ck + 1 < 8) {
            const char* src = wsrc + (size_t)(ck + 1) * 16384;
            char* dst = (char*)sW[(ck + 1) & 1];
#pragma unroll
            for (int c = 0; c < 4; ++c)
                gload_lds16(src + (size_t)(tid + c * 256) * 16,
                            dst + (size_t)(tid + c * 256) * 16);
        }
        const float* wcp = sW[ck & 1];
#pragma unroll 4
        for (int k4 = 0; k4 < 16; ++k4) {
            float4 hv = *(const float4*)&ha[ck * 64 + k4 * 4];
            const float* hvf = (const float*)&hv;
#pragma unroll
            for (int kk = 0; kk < 4; ++kk) {
                float4 wv = *(const float4*)&wcp[(k4 * 4 + kk) * GAT_F + f4];
                acc.x = fmaf(hvf[kk], wv.x, acc.x);
                acc.y = fmaf(hvf[kk], wv.y, acc.y);
                acc.z = fmaf(hvf[kk], wv.z, acc.z);
                acc.w = fmaf(hvf[kk], wv.w, acc.w);
            }
        }
    }

    // wh1/wh2 projections (reduce over f within 16-lane groups)
    float4 a1 = *(const float4*)&a[f4];
    float4 a2 = *(const float4*)&a[GAT_F + f4];
    float pa = acc.x*a1.x + acc.y*a1.y + acc.z*a1.z + acc.w*a1.w;
    float pb = acc.x*a2.x + acc.y*a2.y + acc.z*a2.z + acc.w*a2.w;
#pragma unroll
    for (int m = 1; m < 16; m <<= 1) {
        pa += __shfl_xor(pa, m);
        pb += __shfl_xor(pb, m);
    }
    if ((tid & 15) == 0) {
        wh1[r0 + rp] = pa;
        wh2[r0 + rp] = pb;
        smax[rp] = enc_f32(pb);
    }

    // bf16 split -> LDS transpose buffers
    const float* af = (const float*)&acc;
#pragma unroll
    for (int e = 0; e < 4; ++e) {
        float v = af[e];
        sTh[f4 + e][rp] = (unsigned short)f2bf_trunc(v);
        sTl[f4 + e][rp] = (unsigned short)f2bf_trunc(v - bfhi(v));
    }
    __syncthreads();

    {   // write out WhT rows: thread = (f 0..63, rq 0..3) -> 4 bf16 = 8B
        const int f = tid >> 2, rq = tid & 3;
        uint2 vh = *(const uint2*)&sTh[f][rq * 4];
        uint2 vl = *(const uint2*)&sTl[f][rq * 4];
        *(uint2*)&whtHi[(size_t)f * GAT_N + r0 + rq * 4] = vh;
        *(uint2*)&whtLo[(size_t)f * GAT_N + r0 + rq * 4] = vl;
    }
    if (tid == 0) {
        unsigned m = smax[0];
#pragma unroll
        for (int r = 1; r < 16; ++r) m = max(m, smax[r]);
        atomicMax(mw2, m);
    }
}

// ---------------------------------------------------------------- kernel 2
// grid (128, 8), block 256 (4 waves x 16 rows = 64 rows/block).
// Per 64-j tile: phase A computes p in registers laid out as the MFMA
// A-fragment (lane = (row l&15, jgroup l>>4), 8 j per kstep) from one
// uint64 adjacency bitword per lane; PV is 24 mfma_f32_16x16x32_bf16
// (2 ksteps x 4 fblocks x 3 split terms). WhT tiles (bf16, [f][j])
// staged 2x(hi+lo) double-buffered, XOR-swizzled via pre-swizzled
// global_load_lds SOURCE; ds_read_b128 B-frags conflict-free.
__global__ __launch_bounds__(256, 3) void k_attend(
    const unsigned long long* __restrict__ packed,
    const unsigned short* __restrict__ whtHi,
    const unsigned short* __restrict__ whtLo,
    const float* __restrict__ wh1, const float* __restrict__ wh2,
    const unsigned int* __restrict__ mw2,
    float* __restrict__ po, float* __restrict__ pl)
{
    __shared__ char sB[2][16384];             // [buf][hi 8KB | lo 8KB]

    const int tid  = threadIdx.x;
    const int w    = tid >> 6;
    const int lane = tid & 63;
    const int fl   = lane & 15;
    const int jg   = lane >> 4;
    const int rw   = blockIdx.x * 64 + w * 16;
    const int j0   = blockIdx.y * JCHUNK;

    const float Mw2 = dec_f32(*mw2);
    const float ai  = wh1[rw + fl];           // this lane's row
    const float Mi  = lrelu(ai + Mw2);        // safe rowmax bound

    // staging: dest granule G (16B) at [f=G>>3][g=G&7]; source pre-swizzled
    const char* ssrc[4]; int sdst[4];
#pragma unroll
    for (int c = 0; c < 4; ++c) {
        int G = tid + (c & 1) * 256;
        int f = G >> 3, g = G & 7;
        const unsigned short* base = (c < 2) ? whtHi : whtLo;
        ssrc[c] = (const char*)(base + (size_t)f * GAT_N + j0 + ((g ^ (f & 7)) * 8));
        sdst[c] = ((c < 2) ? 0 : 8192) + G * 16;
    }

    // B-frag byte offsets within a buffer (nb folds into +nb*2048 immediate)
    const int off0 = fl * 128 + (((0 * 4 + jg) ^ (fl & 7)) * 16);
    const int off1 = fl * 128 + (((1 * 4 + jg) ^ (fl & 7)) * 16);

    const unsigned long long* mp = packed + (size_t)(rw + fl) * NWORDS + (j0 >> 6);
    const float* wp = wh2 + j0 + jg * 8;

    // ---- prologue: stage tile 0, prefetch tile-0 mask/wh2
    {
#pragma unroll
        for (int c = 0; c < 4; ++c)
            gload_lds16(ssrc[c], (char*)sB[0] + sdst[c]);
    }
    unsigned long long amc = mp[0];
    float4 wc[4];
#pragma unroll
    for (int q = 0; q < 4; ++q)
        wc[q] = *(const float4*)(wp + (q >> 1) * 32 + (q & 1) * 4);

    f32x4 acc[4] = {};                        // C tiles for 4 f-blocks
    float psum = 0.f;

    for (int t = 0; t < NTILES; ++t) {
        const int cur = t & 1;
        __syncthreads();                      // sB[cur] staged & visible

        // issue next-tile staging + reg prefetch
        if (t + 1 < NTILES) {
#pragma unroll
            for (int c = 0; c < 4; ++c)
                gload_lds16(ssrc[c] + (size_t)(t + 1) * 128,
                            (char*)sB[cur ^ 1] + sdst[c]);
        }
        const int tn = (t + 1 < NTILES) ? t + 1 : t;
        unsigned long long amn = mp[tn];
        float4 wn[4];
#pragma unroll
        for (int q = 0; q < 4; ++q)
            wn[q] = *(const float4*)(wp + tn * TJ + (q >> 1) * 32 + (q & 1) * 4);

        const char* sbc = sB[cur];
#pragma unroll
        for (int s = 0; s < 2; ++s) {         // kstep: j = s*32 + jg*8 + e
            const unsigned m8 = (unsigned)(amc >> (s * 32 + jg * 8)) & 0xFFu;
            float pv[8];
#pragma unroll
            for (int hh = 0; hh < 2; ++hh) {
                const float* bvf = (const float*)&wc[s * 2 + hh];
#pragma unroll
                for (int e = 0; e < 4; ++e) {
                    float sc = lrelu(ai + bvf[e]);
                    float pe = __expf(sc - Mi);
                    pv[hh * 4 + e] = ((m8 >> (hh * 4 + e)) & 1u) ? pe : 0.f;
                }
            }
            short8 ph, plo;
#pragma unroll
            for (int e = 0; e < 8; ++e) {
                psum  += pv[e];
                ph[e]  = f2bf_trunc(pv[e]);
                plo[e] = f2bf_trunc(pv[e] - bfhi(pv[e]));
            }
            const int offs = s ? off1 : off0;
#pragma unroll
            for (int nb = 0; nb < 4; ++nb) {
                short8 bh = *(const short8*)(sbc + offs + nb * 2048);
                short8 bl = *(const short8*)(sbc + 8192 + offs + nb * 2048);
                acc[nb] = __builtin_amdgcn_mfma_f32_16x16x32_bf16(ph,  bh, acc[nb], 0, 0, 0);
                acc[nb] = __builtin_amdgcn_mfma_f32_16x16x32_bf16(plo, bh, acc[nb], 0, 0, 0);
                acc[nb] = __builtin_amdgcn_mfma_f32_16x16x32_bf16(ph,  bl, acc[nb], 0, 0, 0);
            }
        }
        amc = amn;
#pragma unroll
        for (int q = 0; q < 4; ++q) wc[q] = wn[q];
    }

    // ---- epilogue: row sums (4 jg-groups hold partial sums per row)
    psum += __shfl_xor(psum, 16);
    psum += __shfl_xor(psum, 32);
    if (lane < 16)
        pl[(size_t)blockIdx.y * GAT_N + rw + lane] = psum;

    // C layout (m89): col = lane&15 (=f within block), row = (lane>>4)*4 + reg
    const size_t ob = ((size_t)blockIdx.y * GAT_N + rw + jg * 4) * GAT_F + fl;
#pragma unroll
    for (int nb = 0; nb < 4; ++nb) {
#pragma unroll
        for (int r = 0; r < 4; ++r)
            po[ob + (size_t)r * GAT_F + nb * 16] = acc[nb][r];
    }
}

// ---------------------------------------------------------------- kernel 3
__global__ __launch_bounds__(256) void k_merge(
    const float* __restrict__ po, const float* __restrict__ pl,
    float* __restrict__ out)
{
    const int idx = blockIdx.x * 256 + threadIdx.x;   // = i*64 + f
    const int i = idx >> 6;
    float s = 0.f, ls = 0.f;
#pragma unroll
    for (int y = 0; y < JSPLIT; ++y) {
        s  += po[(size_t)y * GAT_N * GAT_F + idx];
        ls += pl[(size_t)y * GAT_N + i];
    }
    out[idx] = s / ls;
}

// ---------------------------------------------------------------- launch
extern "C" void kernel_launch(void* const* d_in, const int* in_sizes, int n_in,
                              void* d_out, int out_size, void* d_ws, size_t ws_size,
                              hipStream_t stream) {
    (void)in_sizes; (void)n_in; (void)out_size; (void)ws_size;
    const float* h   = (const float*)d_in[0];
    const int*   adj = (const int*)d_in[1];
    const float* W   = (const float*)d_in[2];
    const float* a   = (const float*)d_in[3];
    float* out = (float*)d_out;

    char* wsb = (char*)d_ws;
    float*              wh1    = (float*)(wsb);                     // 32 KB
    float*              wh2    = (float*)(wsb + 32768);             // 32 KB
    unsigned int*       mw2    = (unsigned int*)(wsb + 65536);      // 4 B
    unsigned long long* packed = (unsigned long long*)(wsb + 131072); // 8 MB
    unsigned short*     whtHi  = (unsigned short*)(wsb + 8519680);  // 1 MB
    unsigned short*     whtLo  = (unsigned short*)(wsb + 9568256);  // 1 MB
    float*              po     = (float*)(wsb + 10616832);          // 16 MB
    float*              pl     = (float*)(wsb + 27394048);          // 256 KB

    hipMemsetAsync(mw2, 0, 4, stream);        // enc: 0 < every real value
    k_pack  <<<1024, 256, 0, stream>>>(adj, packed);
    k_wh    <<<GAT_N / 16, 256, 0, stream>>>(h, W, a, wh1, wh2, mw2, whtHi, whtLo);
    k_attend<<<dim3(GAT_N / 64, JSPLIT), 256, 0, stream>>>(packed, whtHi, whtLo,
                                                           wh1, wh2, mw2, po, pl);
    k_merge <<<GAT_N * GAT_F / 256, 256, 0, stream>>>(po, pl, out);
}